// Round 6
// baseline (54274.310 us; speedup 1.0000x reference)
//
#include <hip/hip_runtime.h>
#include <stdint.h>

typedef unsigned long long u64;

#define Bq 64
#define Tq 256
#define Hq 512
#define Eq 512
#define Vq 32000
#define NBLK 512

__device__ __forceinline__ float sigmoid_f(float x) { return 1.0f / (1.0f + expf(-x)); }

__device__ __forceinline__ unsigned f2sortable(float f) {
    unsigned u = __float_as_uint(f);
    return (u & 0x80000000u) ? ~u : (u | 0x80000000u);
}

// async global->LDS, 16B per lane; LDS dest is wave-uniform base + lane*16
__device__ __forceinline__ void gl_lds16(const float* g, float* l) {
    __builtin_amdgcn_global_load_lds(
        (const __attribute__((address_space(1))) void*)g,
        (__attribute__((address_space(3))) void*)l, 16, 0, 0);
}

#define DOT4(acc, a, wv) \
    acc = fmaf((a).w, (wv).w, fmaf((a).z, (wv).z, fmaf((a).y, (wv).y, fmaf((a).x, (wv).x, (acc)))))

// ---------------------------------------------------------------------------
// Hierarchical monotonic grid barrier. 32 groups x 16 blocks arrive on
// separate cache lines (parallel serialization), group-finishers arrive on a
// global line, last sets gen=n. Monotonic counters -> no reset races.
// Correct because all 512 blocks are co-resident (68KB LDS -> 2 blocks/CU).
// ---------------------------------------------------------------------------
__device__ __forceinline__ void gbar(unsigned* bar, int blk, unsigned n) {
    __syncthreads();
    if (threadIdx.x == 0) {
        __threadfence();
        const int grp = blk >> 4;                 // 32 groups of 16
        unsigned prev = __hip_atomic_fetch_add(&bar[grp * 32], 1u,
                            __ATOMIC_ACQ_REL, __HIP_MEMORY_SCOPE_AGENT);
        if (prev == n * 16u - 1u) {
            unsigned gp = __hip_atomic_fetch_add(&bar[1024], 1u,
                            __ATOMIC_ACQ_REL, __HIP_MEMORY_SCOPE_AGENT);
            if (gp == n * 32u - 1u)
                __hip_atomic_store(&bar[1056], n, __ATOMIC_RELEASE,
                                   __HIP_MEMORY_SCOPE_AGENT);
        }
        while (__hip_atomic_load(&bar[1056], __ATOMIC_ACQUIRE,
                                 __HIP_MEMORY_SCOPE_AGENT) < n)
            __builtin_amdgcn_s_sleep(1);
        __threadfence();
    }
    __syncthreads();
}

// ---------------------------------------------------------------------------
// LDS layout per block (floats), 17408 total = 68KB:
//   [    0,  4096)  L0 weights: 8 rows x 128 f4 (persistent, staged once)
//   [ 4096,  8192)  L1 weights
//   [ 8192,  9216)  LSTM red [4][4][64] / FC argmax redm u64[256]
//   [ 9216, 13312)  FC buffer 0 (W 2048 | A 2048)
//   [13312, 17408)  FC buffer 1
// ---------------------------------------------------------------------------

// LSTM phase: block = one hidden unit h; weights already resident in LDS.
__device__ __forceinline__ void lstm_phase(
    float* lds, int layer, int h,
    const float* __restrict__ emb, const int* __restrict__ xcol,
    const u64* __restrict__ amax_in,
    const float* __restrict__ inpT, const float* __restrict__ hprevT,
    float* __restrict__ houtT, float* __restrict__ cstate,
    const float* __restrict__ bih, const float* __restrict__ bhh,
    int t, int is_layer0)
{
    const float4* wlds = (const float4*)(lds + layer * 4096);
    float* red = lds + 8192;
    const int tid  = threadIdx.x;
    const int wave = __builtin_amdgcn_readfirstlane(tid >> 6);
    const int lane = tid & 63;

    const int part = wave >> 1;
    const int kq0  = (wave & 1) << 6;

    float acc0 = 0.f, acc1 = 0.f, acc2 = 0.f, acc3 = 0.f;

    if (part == 0 && is_layer0) {
        int row = (t == 0) ? xcol[lane * Tq] : (int)(~(unsigned)amax_in[lane]);
        const float4* a4 = (const float4*)(emb + (size_t)row * Eq);
        #pragma unroll 4
        for (int i = 0; i < 64; ++i) {
            float4 a = a4[kq0 + i];
            int kq = kq0 + i;
            float4 w0 = wlds[0 * 128 + kq];
            float4 w1 = wlds[1 * 128 + kq];
            float4 w2 = wlds[2 * 128 + kq];
            float4 w3 = wlds[3 * 128 + kq];
            DOT4(acc0, a, w0); DOT4(acc1, a, w1);
            DOT4(acc2, a, w2); DOT4(acc3, a, w3);
        }
    } else {
        const float4* a4 = (const float4*)(part ? hprevT : inpT);
        #pragma unroll 4
        for (int i = 0; i < 64; ++i) {
            int kq = kq0 + i;
            float4 a = a4[kq * 64 + lane];
            float4 w0 = wlds[(part * 4 + 0) * 128 + kq];
            float4 w1 = wlds[(part * 4 + 1) * 128 + kq];
            float4 w2 = wlds[(part * 4 + 2) * 128 + kq];
            float4 w3 = wlds[(part * 4 + 3) * 128 + kq];
            DOT4(acc0, a, w0); DOT4(acc1, a, w1);
            DOT4(acc2, a, w2); DOT4(acc3, a, w3);
        }
    }

    red[(wave * 4 + 0) * 64 + lane] = acc0;
    red[(wave * 4 + 1) * 64 + lane] = acc1;
    red[(wave * 4 + 2) * 64 + lane] = acc2;
    red[(wave * 4 + 3) * 64 + lane] = acc3;
    __syncthreads();

    if (wave == 0) {
        float gi = red[(0*4+0)*64+lane] + red[(1*4+0)*64+lane] + red[(2*4+0)*64+lane] + red[(3*4+0)*64+lane]
                 + bih[0 * Hq + h] + bhh[0 * Hq + h];
        float gf = red[(0*4+1)*64+lane] + red[(1*4+1)*64+lane] + red[(2*4+1)*64+lane] + red[(3*4+1)*64+lane]
                 + bih[1 * Hq + h] + bhh[1 * Hq + h];
        float gg = red[(0*4+2)*64+lane] + red[(1*4+2)*64+lane] + red[(2*4+2)*64+lane] + red[(3*4+2)*64+lane]
                 + bih[2 * Hq + h] + bhh[2 * Hq + h];
        float go = red[(0*4+3)*64+lane] + red[(1*4+3)*64+lane] + red[(2*4+3)*64+lane] + red[(3*4+3)*64+lane]
                 + bih[3 * Hq + h] + bhh[3 * Hq + h];
        float cold = cstate[h * 64 + lane];
        float cn = sigmoid_f(gf) * cold + sigmoid_f(gi) * tanhf(gg);
        float hn = sigmoid_f(go) * tanhf(cn);
        cstate[h * 64 + lane] = cn;
        houtT[(h >> 2) * 256 + lane * 4 + (h & 3)] = hn;
    }
}

// FC phase: 64-row tile, 4 waves, K=512; 16 chunks of 32k, double-buffered
// global_load_lds staging; 8x8 register outer product per lane.
__device__ __forceinline__ void fc_phase(
    float* lds, int v0,
    const float* __restrict__ hT, const float* __restrict__ Wfc,
    const float* __restrict__ bfc, float* __restrict__ out,
    u64* __restrict__ amax, int write_out)
{
    const int tid  = threadIdx.x;
    const int wave = __builtin_amdgcn_readfirstlane(tid >> 6);
    const int lane = tid & 63;
    const int rgrp = lane >> 3;
    const int bgrp = lane & 7;

    float acc[8][8];
    #pragma unroll
    for (int j = 0; j < 8; ++j)
        #pragma unroll
        for (int i = 0; i < 8; ++i) acc[j][i] = 0.f;

    // chunk = 32 k (8 f4). W tile 64r x 8 f4 swizzled (s ^ (r>>3)); A tile
    // 8 kq x 64 b with b-swizzle (round-3 proven).
#define STAGE_CHUNK(cc, dst)                                                  \
    {                                                                         \
        _Pragma("unroll")                                                     \
        for (int it = 0; it < 2; ++it) {                                      \
            int g = it * 256 + tid;                                           \
            int r = g >> 3, sp = g & 7;                                       \
            gl_lds16(Wfc + (size_t)(v0 + r) * 512 + (cc) * 32                 \
                         + (((sp ^ (r >> 3)) & 7) << 2),                      \
                     (dst) + it * 1024 + wave * 256);                         \
        }                                                                     \
        _Pragma("unroll")                                                     \
        for (int it = 0; it < 2; ++it) {                                      \
            int g = it * 256 + tid;                                           \
            int kqr = g >> 6, u = g & 63;                                     \
            int b = (u & 56) | ((u & 7) ^ (u >> 3));                          \
            gl_lds16(hT + (size_t)((cc) * 8 + kqr) * 256 + b * 4,             \
                     (dst) + 2048 + it * 1024 + wave * 256);                  \
        }                                                                     \
    }

    float* buf0 = lds + 9216;
    float* buf1 = lds + 13312;
    float* cur = buf0;
    float* nxt = buf1;

    STAGE_CHUNK(0, cur)
    __syncthreads();

    for (int c = 0; c < 16; ++c) {
        if (c < 15) STAGE_CHUNK(c + 1, nxt)

        #pragma unroll
        for (int kq = 0; kq < 2; ++kq) {
            const int sl = wave * 2 + kq;         // k f4-slot 0..7 in chunk
            float4 wv[8], av[8];
            #pragma unroll
            for (int j = 0; j < 8; ++j)
                wv[j] = *(const float4*)(cur + (((rgrp * 8 + j) * 8 + ((sl ^ rgrp) & 7)) << 2));
            #pragma unroll
            for (int i = 0; i < 8; ++i)
                av[i] = *(const float4*)(cur + 2048 + sl * 256 + ((bgrp * 8 + (i ^ bgrp)) << 2));
            #pragma unroll
            for (int j = 0; j < 8; ++j)
                #pragma unroll
                for (int i = 0; i < 8; ++i)
                    DOT4(acc[j][i], av[i], wv[j]);
        }

        __syncthreads();                          // also drains nxt's DMA
        float* tmp = cur; cur = nxt; nxt = tmp;
    }
#undef STAGE_CHUNK

    // cross-wave K reduction into accbuf (sequential, 4 passes — round 3)
    float* accbuf = buf0;
    for (int w = 0; w < 4; ++w) {
        if (wave == w) {
            #pragma unroll
            for (int j = 0; j < 8; ++j) {
                float* p = accbuf + (rgrp * 8 + j) * 64 + bgrp * 8;
                if (w == 0) {
                    *(float4*)p       = make_float4(acc[j][0], acc[j][1], acc[j][2], acc[j][3]);
                    *(float4*)(p + 4) = make_float4(acc[j][4], acc[j][5], acc[j][6], acc[j][7]);
                } else {
                    float4 a0 = *(const float4*)p;
                    float4 a1 = *(const float4*)(p + 4);
                    a0.x += acc[j][0]; a0.y += acc[j][1]; a0.z += acc[j][2]; a0.w += acc[j][3];
                    a1.x += acc[j][4]; a1.y += acc[j][5]; a1.z += acc[j][6]; a1.w += acc[j][7];
                    *(float4*)p       = a0;
                    *(float4*)(p + 4) = a1;
                }
            }
        }
        __syncthreads();
    }

    // bias + per-batch argmax + (last step) logit store
    const int b  = lane;
    const int rq = wave;                // 16 rows per wave
    float best = -__builtin_huge_valf();
    int bi = 0;
    float lg[16];
    #pragma unroll
    for (int n = 0; n < 16; ++n) {
        int r = rq * 16 + n;
        float v = accbuf[r * 64 + b] + bfc[v0 + r];
        lg[n] = v;
        if (v > best) { best = v; bi = v0 + r; }   // '>' keeps smallest index
    }
    u64 pack = ((u64)f2sortable(best) << 32) | (u64)(~(unsigned)bi);

    u64* redm = (u64*)(lds + 8192);
    redm[rq * 64 + b] = pack;
    __syncthreads();
    if (rq == 0) {
        u64 m  = redm[b];
        u64 m1 = redm[64 + b];  if (m1 > m) m = m1;
        u64 m2 = redm[128 + b]; if (m2 > m) m = m2;
        u64 m3 = redm[192 + b]; if (m3 > m) m = m3;
        atomicMax(&amax[b], m);
    }

    if (write_out) {
        #pragma unroll
        for (int n = 0; n < 16; ++n)
            out[(size_t)b * Vq + v0 + rq * 16 + n] = lg[n];
    }
}

// ---------------------------------------------------------------------------
// Persistent kernel: 512 blocks x 256 threads, 68KB LDS -> 2 blocks/CU,
// all 512 co-resident (136KB of 160KB LDS/CU). 3 barriers per step.
// ---------------------------------------------------------------------------
__global__ __launch_bounds__(256, 2) void fused_kernel(
    const int* __restrict__ x, const float* __restrict__ emb,
    const float* __restrict__ Wih, const float* __restrict__ Whh,
    const float* __restrict__ bih, const float* __restrict__ bhh,
    const float* __restrict__ Wfc, const float* __restrict__ bfc,
    float* __restrict__ out, float* __restrict__ ws)
{
    __shared__ float lds[17408];                 // 68KB
    const int tid = threadIdx.x;
    const int blk = blockIdx.x;
    const int h   = blk;                         // this block's hidden unit

    float* h0T[2] = { ws,          ws + 32768 };
    float* h1T[2] = { ws + 65536,  ws + 98304 };
    float* c0 = ws + 131072;
    float* c1 = ws + 163840;
    u64* amax = (u64*)(ws + 196608);             // 64 u64
    unsigned* bar = (unsigned*)(ws + 196736);    // barrier counters (zeroed)

    // ---- stage BOTH layers' weights for unit h into LDS, once ----
    const size_t WL = (size_t)4 * Hq * 512;
    #pragma unroll
    for (int l = 0; l < 2; ++l) {
        const float4* Wih4 = (const float4*)(Wih + l * WL);
        const float4* Whh4 = (const float4*)(Whh + l * WL);
        float4* dstw = (float4*)(lds + l * 4096);
        #pragma unroll
        for (int i = 0; i < 4; ++i) {
            int g   = i * 256 + tid;             // 0..1023
            int s   = g >> 7;
            int off = g & 127;
            const float4* src = (s < 4) ? Wih4 : Whh4;
            dstw[g] = src[(size_t)((s & 3) * Hq + h) * 128 + off];
        }
    }
    __syncthreads();

    unsigned bn = 0;

    for (int t = 0; t < Tq; ++t) {
        const int rd = t & 1, wr = rd ^ 1;

        // P1: layer 0 (consumes amax from previous step's FC)
        lstm_phase(lds, 0, h, emb, x, amax,
                   nullptr, h0T[rd], h0T[wr], c0, bih, bhh, t, 1);
        gbar(bar, blk, ++bn);

        // P2: layer 1; block 511 also resets amax (consumed P1, written P3)
        if (blk == NBLK - 1 && tid < 64) amax[tid] = 0;
        lstm_phase(lds, 1, h, emb, x, amax,
                   h0T[wr], h1T[rd], h1T[wr], c1,
                   bih + 4 * Hq, bhh + 4 * Hq, t, 0);
        gbar(bar, blk, ++bn);

        // P3: FC head + argmax (blocks 500..511 idle)
        if (blk < 500)
            fc_phase(lds, blk * 64, h1T[wr], Wfc, bfc, out, amax,
                     (t == Tq - 1) ? 1 : 0);
        gbar(bar, blk, ++bn);
    }
}

extern "C" void kernel_launch(void* const* d_in, const int* in_sizes, int n_in,
                              void* d_out, int out_size, void* d_ws, size_t ws_size,
                              hipStream_t stream)
{
    const int*   x   = (const int*)d_in[0];
    const float* emb = (const float*)d_in[1];
    const float* Wih = (const float*)d_in[2];
    const float* Whh = (const float*)d_in[3];
    const float* bih = (const float*)d_in[4];
    const float* bhh = (const float*)d_in[5];
    const float* Wfc = (const float*)d_in[6];
    const float* bfc = (const float*)d_in[7];
    float* outp = (float*)d_out;
    float* wsf  = (float*)d_ws;

    // zero h/c state + amax + barrier area: 196736 + 1088 = 197824 floats
    hipMemsetAsync(d_ws, 0, 197824 * sizeof(float), stream);

    fused_kernel<<<NBLK, 256, 0, stream>>>(x, emb, Wih, Whh, bih, bhh,
                                           Wfc, bfc, outp, wsf);
}